// Round 1
// baseline (1650.162 us; speedup 1.0000x reference)
//
#include <hip/hip_runtime.h>
#include <hip/hip_bf16.h>
#include <math.h>

typedef __bf16 bf16_t;
typedef __bf16 bf16x8 __attribute__((ext_vector_type(8)));
typedef __bf16 bf16x4 __attribute__((ext_vector_type(4)));
typedef float f32x4 __attribute__((ext_vector_type(4)));

// B=64, S=4096, DEC=512, ENC=1024, A=256

// ---------------- dec_proj = decoder_hidden @ W_dec : (64,256) ----------------
__global__ __launch_bounds__(256) void k_dec_proj(const float* __restrict__ dh,
                                                  const float* __restrict__ Wd,
                                                  float* __restrict__ dec_proj) {
    int b = blockIdx.x, a = threadIdx.x;
    const float* dhb = dh + b * 512;
    float acc = 0.f;
    #pragma unroll 8
    for (int k = 0; k < 512; ++k) acc += dhb[k] * Wd[k * 256 + a];
    dec_proj[b * 256 + a] = acc;
}

// ---------------- W_encT[a][k] = bf16(W_enc[k][a]) : (256,1024) ----------------
__global__ __launch_bounds__(256) void k_wenc_t(const float* __restrict__ Wenc,
                                                bf16_t* __restrict__ WencT) {
    __shared__ float tile[64][65];
    int k0 = blockIdx.x * 64, a0 = blockIdx.y * 64, tid = threadIdx.x;
    #pragma unroll
    for (int it = 0; it < 16; ++it) {
        int e = it * 256 + tid;
        int kk = e >> 6, aa = e & 63;
        tile[kk][aa] = Wenc[(k0 + kk) * 256 + a0 + aa];
    }
    __syncthreads();
    #pragma unroll
    for (int it = 0; it < 16; ++it) {
        int e = it * 256 + tid;
        int aa = e >> 6, kk = e & 63;
        WencT[(size_t)(a0 + aa) * 1024 + k0 + kk] = (bf16_t)tile[kk][aa];
    }
}

// ---------------- fused scores: score[m] = v . tanh(dec_proj[b] + enc[m] @ W_enc) ----------------
// Block: 256 threads (4 waves). Tile: M=64 rows (one b), N=256 (all A), K=1024.
// Wave w computes 64x64 strip (cols 64w..64w+63) via 4x4 mfma_f32_16x16x32_bf16 tiles.
__global__ __launch_bounds__(256) void k_scores(const float* __restrict__ enc,
                                                const bf16_t* __restrict__ WencT,
                                                const float* __restrict__ dec_proj,
                                                const float* __restrict__ v,
                                                float* __restrict__ scores) {
    __shared__ bf16_t Abuf[64][72];    // 64 rows x 64 k, pad 8 (16B) to break conflicts
    __shared__ bf16_t Bbuf[256][72];   // 256 cols x 64 k
    __shared__ float dec_s[256];
    __shared__ float v_s[256];
    __shared__ float score_s[64];

    const int tid  = threadIdx.x;
    const int R    = blockIdx.x * 64;     // global row base (m = b*4096 + s)
    const int b    = R >> 12;             // R / 4096
    const int wv   = tid >> 6;            // wave 0..3
    const int lane = tid & 63;
    const int lr   = lane & 15;           // A-row / B-col within 16-tile
    const int lg   = lane >> 4;           // k-group 0..3 (8 k each)

    dec_s[tid] = dec_proj[b * 256 + tid];
    v_s[tid]   = v[tid];
    if (tid < 64) score_s[tid] = 0.f;

    f32x4 zero = {0.f, 0.f, 0.f, 0.f};
    f32x4 acc[4][4];
    #pragma unroll
    for (int i = 0; i < 4; ++i)
        #pragma unroll
        for (int j = 0; j < 4; ++j) acc[i][j] = zero;

    const float* encR = enc + (size_t)R * 1024;

    for (int kb = 0; kb < 16; ++kb) {
        __syncthreads();
        // stage A: 64 rows x 64 k, fp32 -> bf16  (1024 float4 loads / 256 threads)
        #pragma unroll
        for (int rep = 0; rep < 4; ++rep) {
            int idx = rep * 256 + tid;
            int row = idx >> 4, c4 = idx & 15;
            const float4 val = *(const float4*)(encR + (size_t)row * 1024 + kb * 64 + c4 * 4);
            bf16x4 o;
            o.x = (bf16_t)val.x; o.y = (bf16_t)val.y; o.z = (bf16_t)val.z; o.w = (bf16_t)val.w;
            *(bf16x4*)&Abuf[row][c4 * 4] = o;
        }
        // stage B: 256 cols x 64 k bf16 (already transposed, K-major contiguous)
        #pragma unroll
        for (int rep = 0; rep < 8; ++rep) {
            int idx = rep * 256 + tid;
            int arow = idx >> 3, c8 = idx & 7;
            *(bf16x8*)&Bbuf[arow][c8 * 8] =
                *(const bf16x8*)(WencT + (size_t)arow * 1024 + kb * 64 + c8 * 8);
        }
        __syncthreads();
        #pragma unroll
        for (int kk = 0; kk < 2; ++kk) {
            const int ko = kk * 32 + lg * 8;
            bf16x8 af[4], bfr[4];
            #pragma unroll
            for (int tm = 0; tm < 4; ++tm) af[tm] = *(const bf16x8*)&Abuf[tm * 16 + lr][ko];
            #pragma unroll
            for (int tn = 0; tn < 4; ++tn) bfr[tn] = *(const bf16x8*)&Bbuf[wv * 64 + tn * 16 + lr][ko];
            #pragma unroll
            for (int tm = 0; tm < 4; ++tm)
                #pragma unroll
                for (int tn = 0; tn < 4; ++tn)
                    acc[tm][tn] = __builtin_amdgcn_mfma_f32_16x16x32_bf16(af[tm], bfr[tn], acc[tm][tn], 0, 0, 0);
        }
    }

    // epilogue: C/D layout (16x16): col = lane&15, row = (lane>>4)*4 + reg
    #pragma unroll
    for (int tm = 0; tm < 4; ++tm) {
        #pragma unroll
        for (int r = 0; r < 4; ++r) {
            float sum = 0.f;
            #pragma unroll
            for (int tn = 0; tn < 4; ++tn) {
                int col = wv * 64 + tn * 16 + lr;
                sum += v_s[col] * tanhf(dec_s[col] + acc[tm][tn][r]);
            }
            // reduce over the 16 lanes (lr) that share this row
            sum += __shfl_xor(sum, 1);
            sum += __shfl_xor(sum, 2);
            sum += __shfl_xor(sum, 4);
            sum += __shfl_xor(sum, 8);
            if (lr == 0) atomicAdd(&score_s[tm * 16 + lg * 4 + r], sum);
        }
    }
    __syncthreads();
    if (tid < 64) scores[R + tid] = score_s[tid];
}

// ---------------- masked softmax over S, in place in d_out weights region ----------------
__global__ __launch_bounds__(256) void k_softmax(float* __restrict__ sw,
                                                 const int* __restrict__ mask) {
    int b = blockIdx.x, tid = threadIdx.x;
    float vals[16];
    float mx = -3.0e38f;
    #pragma unroll
    for (int i = 0; i < 16; ++i) {
        int s = i * 256 + tid;
        float sc = sw[b * 4096 + s];
        if (mask[b * 4096 + s] != 0) sc = -1e10f;   // where(mask, NEG_INF, scores)
        vals[i] = sc;
        mx = fmaxf(mx, sc);
    }
    #pragma unroll
    for (int off = 1; off < 64; off <<= 1) mx = fmaxf(mx, __shfl_xor(mx, off));
    __shared__ float red[4];
    __shared__ float red2[4];
    if ((tid & 63) == 0) red[tid >> 6] = mx;
    __syncthreads();
    mx = fmaxf(fmaxf(red[0], red[1]), fmaxf(red[2], red[3]));
    float sum = 0.f;
    #pragma unroll
    for (int i = 0; i < 16; ++i) { vals[i] = __expf(vals[i] - mx); sum += vals[i]; }
    #pragma unroll
    for (int off = 1; off < 64; off <<= 1) sum += __shfl_xor(sum, off);
    if ((tid & 63) == 0) red2[tid >> 6] = sum;
    __syncthreads();
    sum = red2[0] + red2[1] + red2[2] + red2[3];
    float inv = 1.0f / sum;
    #pragma unroll
    for (int i = 0; i < 16; ++i) sw[b * 4096 + i * 256 + tid] = vals[i] * inv;
}

// ---------------- context partials: partial[chunk][b][e] = sum_{s in chunk} w[b][s]*enc[b][s][e] ----------------
__global__ __launch_bounds__(256) void k_ctx(const float* __restrict__ enc,
                                             const float* __restrict__ w,
                                             float* __restrict__ partial) {
    int chunk = blockIdx.x, b = blockIdx.y, tid = threadIdx.x;
    float4 acc = {0.f, 0.f, 0.f, 0.f};
    int s0 = chunk * 256;
    const float* base = enc + ((size_t)b * 4096 + s0) * 1024 + tid * 4;
    const float* wb = w + b * 4096 + s0;
    #pragma unroll 4
    for (int i = 0; i < 256; ++i) {
        float ww = wb[i];
        float4 e = *(const float4*)(base + (size_t)i * 1024);
        acc.x += ww * e.x; acc.y += ww * e.y; acc.z += ww * e.z; acc.w += ww * e.w;
    }
    *(float4*)(partial + ((size_t)chunk * 64 + b) * 1024 + tid * 4) = acc;
}

// ---------------- combine partials -> context (64,1024) ----------------
__global__ __launch_bounds__(256) void k_comb(const float* __restrict__ partial,
                                              float* __restrict__ outc) {
    int idx = blockIdx.x * 256 + threadIdx.x;
    float s = 0.f;
    #pragma unroll
    for (int c = 0; c < 16; ++c) s += partial[c * 65536 + idx];
    outc[idx] = s;
}

extern "C" void kernel_launch(void* const* d_in, const int* in_sizes, int n_in,
                              void* d_out, int out_size, void* d_ws, size_t ws_size,
                              hipStream_t stream) {
    const float* dh   = (const float*)d_in[0];   // (64,512)
    const float* enc  = (const float*)d_in[1];   // (64,4096,1024)
    const int*   mask = (const int*)d_in[2];     // (64,4096)
    const float* Wd   = (const float*)d_in[3];   // (512,256)
    const float* Wenc = (const float*)d_in[4];   // (1024,256)
    const float* v    = (const float*)d_in[5];   // (256,)

    float* out  = (float*)d_out;
    float* outc = out;            // context: 64*1024 = 65536 floats
    float* outw = out + 65536;    // weights: 64*4096 = 262144 floats

    float* ws_f     = (float*)d_ws;
    float* dec_proj = ws_f;                               // 16384 floats
    float* partial  = ws_f + 16384;                       // 1048576 floats (16*64*1024)
    bf16_t* WencT   = (bf16_t*)(ws_f + 16384 + 1048576);  // 262144 bf16 (512 KB)

    k_dec_proj<<<64, 256, 0, stream>>>(dh, Wd, dec_proj);
    k_wenc_t<<<dim3(16, 4), 256, 0, stream>>>(Wenc, WencT);
    k_scores<<<4096, 256, 0, stream>>>(enc, WencT, dec_proj, v, outw);
    k_softmax<<<64, 256, 0, stream>>>(outw, mask);
    k_ctx<<<dim3(16, 64), 256, 0, stream>>>(enc, outw, partial);
    k_comb<<<256, 256, 0, stream>>>(partial, outc);
}

// Round 2
// 1582.926 us; speedup vs baseline: 1.0425x; 1.0425x over previous
//
#include <hip/hip_runtime.h>
#include <hip/hip_bf16.h>
#include <math.h>

typedef __bf16 bf16_t;
typedef __bf16 bf16x8 __attribute__((ext_vector_type(8)));
typedef __bf16 bf16x4 __attribute__((ext_vector_type(4)));
typedef float f32x4 __attribute__((ext_vector_type(4)));

// B=64, S=4096, DEC=512, ENC=1024, A=256

__device__ __forceinline__ float fast_tanh(float x) {
    // tanh(x) = 1 - 2/(e^{2x}+1); exact limits at +-inf, ~1e-6 rel error mid-range
    return 1.0f - 2.0f / (__expf(2.0f * x) + 1.0f);
}

// ---------------- dec_proj = decoder_hidden @ W_dec : (64,256) ----------------
__global__ __launch_bounds__(256) void k_dec_proj(const float* __restrict__ dh,
                                                  const float* __restrict__ Wd,
                                                  float* __restrict__ dec_proj) {
    int b = blockIdx.x, a = threadIdx.x;
    const float* dhb = dh + b * 512;
    float acc = 0.f;
    #pragma unroll 8
    for (int k = 0; k < 512; ++k) acc += dhb[k] * Wd[k * 256 + a];
    dec_proj[b * 256 + a] = acc;
}

// ---------------- W_encT[a][k] = bf16(W_enc[k][a]) : (256,1024) ----------------
__global__ __launch_bounds__(256) void k_wenc_t(const float* __restrict__ Wenc,
                                                bf16_t* __restrict__ WencT) {
    __shared__ float tile[64][65];
    int k0 = blockIdx.x * 64, a0 = blockIdx.y * 64, tid = threadIdx.x;
    #pragma unroll
    for (int it = 0; it < 16; ++it) {
        int e = it * 256 + tid;
        int kk = e >> 6, aa = e & 63;
        tile[kk][aa] = Wenc[(k0 + kk) * 256 + a0 + aa];
    }
    __syncthreads();
    #pragma unroll
    for (int it = 0; it < 16; ++it) {
        int e = it * 256 + tid;
        int aa = e >> 6, kk = e & 63;
        WencT[(size_t)(a0 + aa) * 1024 + k0 + kk] = (bf16_t)tile[kk][aa];
    }
}

// ---------------- fused: scores -> mask -> exp -> partial context ----------------
// Block: 256 threads (4 waves), 64 rows (one b each). After the MFMA k-loop the
// block's 64x4KB enc tile is L2-warm; re-read it for the context partial.
// exp without max-subtraction is safe: |score| <~ 10, masked -> exp(-1e10)=0.
__global__ __launch_bounds__(256) void k_fused(const float* __restrict__ enc,
                                               const bf16_t* __restrict__ WencT,
                                               const float* __restrict__ dec_proj,
                                               const float* __restrict__ v,
                                               const int* __restrict__ mask,
                                               float* __restrict__ ew,       // unnormalized weights (B,S)
                                               float* __restrict__ esum,     // per-chunk sum of e (4096)
                                               float* __restrict__ partial)  // per-chunk ctx partial (4096,1024)
{
    __shared__ bf16_t Abuf[64][72];    // 64 rows x 64 k, pad to break conflicts
    __shared__ bf16_t Bbuf[256][72];   // 256 cols x 64 k
    __shared__ float dec_s[256];
    __shared__ float v_s[256];
    __shared__ float score_s[64];

    const int tid  = threadIdx.x;
    const int R    = blockIdx.x * 64;     // global row base (m = b*4096 + s)
    const int b    = R >> 12;             // R / 4096
    const int wv   = tid >> 6;            // wave 0..3
    const int lane = tid & 63;
    const int lr   = lane & 15;           // A-row / B-col within 16-tile
    const int lg   = lane >> 4;           // k-group 0..3 (8 k each)

    dec_s[tid] = dec_proj[b * 256 + tid];
    v_s[tid]   = v[tid];
    if (tid < 64) score_s[tid] = 0.f;

    f32x4 zero = {0.f, 0.f, 0.f, 0.f};
    f32x4 acc[4][4];
    #pragma unroll
    for (int i = 0; i < 4; ++i)
        #pragma unroll
        for (int j = 0; j < 4; ++j) acc[i][j] = zero;

    const float* encR = enc + (size_t)R * 1024;

    for (int kb = 0; kb < 16; ++kb) {
        __syncthreads();
        // stage A: 64 rows x 64 k, fp32 -> bf16
        #pragma unroll
        for (int rep = 0; rep < 4; ++rep) {
            int idx = rep * 256 + tid;
            int row = idx >> 4, c4 = idx & 15;
            const float4 val = *(const float4*)(encR + (size_t)row * 1024 + kb * 64 + c4 * 4);
            bf16x4 o;
            o.x = (bf16_t)val.x; o.y = (bf16_t)val.y; o.z = (bf16_t)val.z; o.w = (bf16_t)val.w;
            *(bf16x4*)&Abuf[row][c4 * 4] = o;
        }
        // stage B: 256 cols x 64 k bf16 (K-major contiguous)
        #pragma unroll
        for (int rep = 0; rep < 8; ++rep) {
            int idx = rep * 256 + tid;
            int arow = idx >> 3, c8 = idx & 7;
            *(bf16x8*)&Bbuf[arow][c8 * 8] =
                *(const bf16x8*)(WencT + (size_t)arow * 1024 + kb * 64 + c8 * 8);
        }
        __syncthreads();
        #pragma unroll
        for (int kk = 0; kk < 2; ++kk) {
            const int ko = kk * 32 + lg * 8;
            bf16x8 af[4], bfr[4];
            #pragma unroll
            for (int tm = 0; tm < 4; ++tm) af[tm] = *(const bf16x8*)&Abuf[tm * 16 + lr][ko];
            #pragma unroll
            for (int tn = 0; tn < 4; ++tn) bfr[tn] = *(const bf16x8*)&Bbuf[wv * 64 + tn * 16 + lr][ko];
            #pragma unroll
            for (int tm = 0; tm < 4; ++tm)
                #pragma unroll
                for (int tn = 0; tn < 4; ++tn)
                    acc[tm][tn] = __builtin_amdgcn_mfma_f32_16x16x32_bf16(af[tm], bfr[tn], acc[tm][tn], 0, 0, 0);
        }
    }

    // epilogue: C/D layout (16x16): col = lane&15, row = (lane>>4)*4 + reg
    #pragma unroll
    for (int tm = 0; tm < 4; ++tm) {
        #pragma unroll
        for (int r = 0; r < 4; ++r) {
            float sum = 0.f;
            #pragma unroll
            for (int tn = 0; tn < 4; ++tn) {
                int col = wv * 64 + tn * 16 + lr;
                sum += v_s[col] * fast_tanh(dec_s[col] + acc[tm][tn][r]);
            }
            sum += __shfl_xor(sum, 1);
            sum += __shfl_xor(sum, 2);
            sum += __shfl_xor(sum, 4);
            sum += __shfl_xor(sum, 8);
            if (lr == 0) atomicAdd(&score_s[tm * 16 + lg * 4 + r], sum);
        }
    }
    __syncthreads();

    // mask + exp (no max needed: scores bounded, masked -> exp(-1e10)=0)
    if (tid < 64) {
        float sc = score_s[tid];
        if (mask[R + tid] != 0) sc = -1e10f;
        float e = __expf(sc);
        score_s[tid] = e;          // now holds e
        ew[R + tid] = e;           // unnormalized weight out
    }
    __syncthreads();

    // per-chunk e-sum (wave 0 reduces 64 values)
    if (tid < 64) {
        float e = score_s[tid];
        #pragma unroll
        for (int off = 1; off < 64; off <<= 1) e += __shfl_xor(e, off);
        if (tid == 0) esum[blockIdx.x] = e;
    }

    // partial context: re-read the (L2-warm) 64x1024 tile; skip masked rows (e==0)
    f32x4 cacc = {0.f, 0.f, 0.f, 0.f};
    const float* basep = encR + tid * 4;
    for (int s = 0; s < 64; ++s) {
        float e = score_s[s];      // LDS broadcast, block-uniform
        if (e != 0.f) {
            float4 ev = *(const float4*)(basep + (size_t)s * 1024);
            cacc.x += e * ev.x; cacc.y += e * ev.y; cacc.z += e * ev.z; cacc.w += e * ev.w;
        }
    }
    *(f32x4*)(partial + (size_t)blockIdx.x * 1024 + tid * 4) = cacc;
}

// ---------------- combine partials -> context, normalized ----------------
__global__ __launch_bounds__(256) void k_ctx_comb(const float* __restrict__ partial,
                                                  const float* __restrict__ esum,
                                                  float* __restrict__ outc) {
    int b = blockIdx.y, ec = blockIdx.x, tid = threadIdx.x;
    int e = ec * 256 + tid;
    float d = 0.f;
    #pragma unroll
    for (int c = 0; c < 64; ++c) d += esum[b * 64 + c];
    float s = 0.f;
    #pragma unroll 8
    for (int c = 0; c < 64; ++c) s += partial[(size_t)(b * 64 + c) * 1024 + e];
    outc[b * 1024 + e] = s / d;
}

// ---------------- normalize weights: outw[b][s] = e / denom[b] ----------------
__global__ __launch_bounds__(256) void k_wnorm(float* __restrict__ ew,
                                               const float* __restrict__ esum) {
    int b = blockIdx.y, sc = blockIdx.x, tid = threadIdx.x;
    float d = 0.f;
    #pragma unroll
    for (int c = 0; c < 64; ++c) d += esum[b * 64 + c];
    int s = sc * 256 + tid;
    ew[b * 4096 + s] = ew[b * 4096 + s] / d;
}

extern "C" void kernel_launch(void* const* d_in, const int* in_sizes, int n_in,
                              void* d_out, int out_size, void* d_ws, size_t ws_size,
                              hipStream_t stream) {
    const float* dh   = (const float*)d_in[0];   // (64,512)
    const float* enc  = (const float*)d_in[1];   // (64,4096,1024)
    const int*   mask = (const int*)d_in[2];     // (64,4096)
    const float* Wd   = (const float*)d_in[3];   // (512,256)
    const float* Wenc = (const float*)d_in[4];   // (1024,256)
    const float* v    = (const float*)d_in[5];   // (256,)

    float* out  = (float*)d_out;
    float* outc = out;            // context: 64*1024 = 65536 floats
    float* outw = out + 65536;    // weights: 64*4096 = 262144 floats

    char* ws = (char*)d_ws;
    float*  dec_proj = (float*)(ws);                         // 65536 B
    float*  esum     = (float*)(ws + 65536);                 // 16384 B (4096 f)
    float*  partial  = (float*)(ws + 81920);                 // 16 MiB (4096*1024 f)
    bf16_t* WencT    = (bf16_t*)(ws + 81920 + 16777216);     // 512 KiB

    k_dec_proj<<<64, 256, 0, stream>>>(dh, Wd, dec_proj);
    k_wenc_t<<<dim3(16, 4), 256, 0, stream>>>(Wenc, WencT);
    k_fused<<<4096, 256, 0, stream>>>(enc, WencT, dec_proj, v, mask, outw, esum, partial);
    k_ctx_comb<<<dim3(4, 64), 256, 0, stream>>>(partial, esum, outc);
    k_wnorm<<<dim3(16, 64), 256, 0, stream>>>(outw, esum);
}